// Round 2
// baseline (380.986 us; speedup 1.0000x reference)
//
#include <hip/hip_runtime.h>
#include <cstdint>
#include <cstddef>

#define M_DIM 4096
#define N_DIM 8192
#define K_DIM 4096

typedef __attribute__((ext_vector_type(4))) int int4v;

// ---------------------------------------------------------------------------
// Pack into MFMA-fragment order (int32 -> int8). R3/R8-verified, identical.
// p = 16-row panel, s = 64-byte kstep, lane l: chunk(p,s) is 1024 B where
// lane l holds row 16p+(l&15), k-bytes s*64 + (l>>4)*16 .. +16.
// ---------------------------------------------------------------------------
__global__ void __launch_bounds__(256) pack_frag(const int* __restrict__ a,
                                                 const int* __restrict__ b,
                                                 unsigned char* __restrict__ pa,
                                                 unsigned char* __restrict__ pb) {
    size_t t = (size_t)blockIdx.x * 256 + threadIdx.x;
    const size_t NA = (size_t)(M_DIM / 16) * (K_DIM / 64) * 64;
    const int* __restrict__ src;
    unsigned char* __restrict__ dst;
    if (t < NA) {
        src = a; dst = pa;
    } else {
        src = b; dst = pb; t -= NA;
    }
    const int l = (int)(t & 63);
    const int s = (int)((t >> 6) & 63);
    const int p = (int)(t >> 12);
    const int* g = src + ((size_t)(16 * p + (l & 15))) * K_DIM + s * 64 + (l >> 4) * 16;
    const int4v* g4 = (const int4v*)g;
    int4v o;
#pragma unroll
    for (int q = 0; q < 4; ++q) {
        int4v v = g4[q];
        o[q] = (v[0] & 0xff) | ((v[1] & 0xff) << 8) | ((v[2] & 0xff) << 16) | (v[3] << 24);
    }
    ((int4v*)dst)[t] = o;
}

// ---------------------------------------------------------------------------
// GEMM: 8-phase schedule (T3+T4+T5), 256(M) x 256(N) block, 512 thr = 8 waves
// (2M x 4N), wave tile 128x64, mfma_i32_16x16x64_i8, BK=64.
// Triple-buffered LDS (3 x 32 KB) so the tile-boundary wait is a COUNTED
// vmcnt(4): the 4 DMA loads for tile T+2 stay in flight across the barrier
// (never drained to 0 in steady state). 4 phases/K-tile in snake order
// (A0B0 -> A0B1 -> A1B1 -> A1B0), each phase = {ds_read frags || issue 1
// global_load_lds -> s_barrier -> lgkmcnt(0) -> setprio(1) -> 8 MFMA ->
// setprio(0) -> s_barrier}. Fragment-packed LDS is linear (lane*16):
// conflict-free (counter-verified 0), no swizzle needed.
// ---------------------------------------------------------------------------
__device__ inline void async_copy16(const unsigned char* g, unsigned char* l) {
    __builtin_amdgcn_global_load_lds(
        (const __attribute__((address_space(1))) void*)g,
        (__attribute__((address_space(3))) void*)l,
        16, 0, 0);
}

#define BAR() __builtin_amdgcn_s_barrier()
#define WAIT_LGKM0() asm volatile("s_waitcnt lgkmcnt(0)" ::: "memory")

__global__ void __launch_bounds__(512, 2) gemm_i8(const unsigned char* __restrict__ Ap,
                                                  const unsigned char* __restrict__ Bp,
                                                  const _Float16* __restrict__ arow,
                                                  const _Float16* __restrict__ acol,
                                                  _Float16* __restrict__ Cout) {
    // buf b at b*32768: A panels [0,16K), B panels [16K,32K)
    __shared__ __align__(16) unsigned char lds[3 * 32768];

    const int tid  = threadIdx.x;
    const int lane = tid & 63;
    const int wave = tid >> 6;   // 0..7
    const int wr   = wave >> 2;  // 0..1  (M half of block)
    const int wc   = wave & 3;   // 0..3  (N quarter of block)
    const int bn   = blockIdx.x; // 0..31 (256 cols)
    const int bm   = blockIdx.y; // 0..15 (256 rows)

    // staging: wave w stages A panels {2w,2w+1} and B panels {2w,2w+1};
    // 4 chunks (= 4 global_load_lds) per wave per K-tile, 1 per phase.
    const unsigned char* aG[2];
    const unsigned char* bG[2];
    int aL[2], bL[2];
#pragma unroll
    for (int r = 0; r < 2; ++r) {
        const int p = 2 * wave + r;
        aG[r] = Ap + (size_t)(bm * 16 + p) * 65536 + lane * 16;
        aL[r] = p * 1024;                 // wave-uniform; HW adds lane*16
        bG[r] = Bp + (size_t)(bn * 16 + p) * 65536 + lane * 16;
        bL[r] = 16384 + p * 1024;
    }

    const int a_off = wr * 8192 + lane * 16;          // af[i]: + i*1024, i=0..7
    const int b_off = 16384 + wc * 4096 + lane * 16;  // bf[j]: + j*1024, j=0..3

    int4v acc[8][4];
#pragma unroll
    for (int i = 0; i < 8; ++i)
#pragma unroll
        for (int j = 0; j < 4; ++j) acc[i][j] = (int4v)0;

    const int NT = K_DIM / 64;  // 64

    // prologue: stage tile 0 -> buf0, tile 1 -> buf1 (8 loads in flight)
#pragma unroll
    for (int t = 0; t < 2; ++t) {
        const size_t gk = (size_t)t * 1024;
        const int lo = t * 32768;
        async_copy16(aG[0] + gk, lds + lo + aL[0]);
        async_copy16(aG[1] + gk, lds + lo + aL[1]);
        async_copy16(bG[0] + gk, lds + lo + bL[0]);
        async_copy16(bG[1] + gk, lds + lo + bL[1]);
    }
    asm volatile("s_waitcnt vmcnt(4)" ::: "memory");  // tile0 landed, tile1 in flight
    BAR();

    int o_cur = 0, o_nxt = 32768, o_pre = 65536;

    for (int T = 0; T < NT; ++T) {
        const bool pre = (T + 2 < NT);            // uniform
        const size_t gk2 = (size_t)(T + 2) * 1024;
        const unsigned char* Ac = lds + o_cur;

        int4v af[4], bf01[2], bf23[2];

        // ---- phase 0: (i 0..3) x (j 0..1) -------------------------------
#pragma unroll
        for (int i = 0; i < 4; ++i)
            af[i] = *(const int4v*)(Ac + a_off + i * 1024);
#pragma unroll
        for (int j = 0; j < 2; ++j)
            bf01[j] = *(const int4v*)(Ac + b_off + j * 1024);
        if (pre) async_copy16(aG[0] + gk2, lds + o_pre + aL[0]);
        BAR();
        WAIT_LGKM0();
        __builtin_amdgcn_s_setprio(1);
#pragma unroll
        for (int i = 0; i < 4; ++i)
#pragma unroll
            for (int j = 0; j < 2; ++j)
                acc[i][j] = __builtin_amdgcn_mfma_i32_16x16x64_i8(af[i], bf01[j],
                                                                  acc[i][j], 0, 0, 0);
        __builtin_amdgcn_s_setprio(0);
        BAR();

        // ---- phase 1: (i 0..3) x (j 2..3) -------------------------------
#pragma unroll
        for (int j = 0; j < 2; ++j)
            bf23[j] = *(const int4v*)(Ac + b_off + (2 + j) * 1024);
        if (pre) async_copy16(aG[1] + gk2, lds + o_pre + aL[1]);
        BAR();
        WAIT_LGKM0();
        __builtin_amdgcn_s_setprio(1);
#pragma unroll
        for (int i = 0; i < 4; ++i)
#pragma unroll
            for (int j = 0; j < 2; ++j)
                acc[i][2 + j] = __builtin_amdgcn_mfma_i32_16x16x64_i8(af[i], bf23[j],
                                                                      acc[i][2 + j], 0, 0, 0);
        __builtin_amdgcn_s_setprio(0);
        BAR();

        // ---- phase 2: (i 4..7) x (j 2..3) -------------------------------
#pragma unroll
        for (int i = 0; i < 4; ++i)
            af[i] = *(const int4v*)(Ac + a_off + (4 + i) * 1024);  // reuse regs
        if (pre) async_copy16(bG[0] + gk2, lds + o_pre + bL[0]);
        BAR();
        WAIT_LGKM0();
        __builtin_amdgcn_s_setprio(1);
#pragma unroll
        for (int i = 0; i < 4; ++i)
#pragma unroll
            for (int j = 0; j < 2; ++j)
                acc[4 + i][2 + j] = __builtin_amdgcn_mfma_i32_16x16x64_i8(af[i], bf23[j],
                                                                          acc[4 + i][2 + j], 0, 0, 0);
        __builtin_amdgcn_s_setprio(0);
        BAR();

        // ---- phase 3: (i 4..7) x (j 0..1), no new reads -----------------
        if (pre) async_copy16(bG[1] + gk2, lds + o_pre + bL[1]);
        BAR();
        __builtin_amdgcn_s_setprio(1);
#pragma unroll
        for (int i = 0; i < 4; ++i)
#pragma unroll
            for (int j = 0; j < 2; ++j)
                acc[4 + i][j] = __builtin_amdgcn_mfma_i32_16x16x64_i8(af[i], bf01[j],
                                                                      acc[4 + i][j], 0, 0, 0);
        __builtin_amdgcn_s_setprio(0);

        // ---- tile boundary: COUNTED wait — tile T+1 done, T+2 in flight --
        if (pre) {
            asm volatile("s_waitcnt vmcnt(4)" ::: "memory");
        } else {
            asm volatile("s_waitcnt vmcnt(0)" ::: "memory");
        }
        BAR();

        const int t0 = o_cur; o_cur = o_nxt; o_nxt = o_pre; o_pre = t0;
    }

    // --- epilogue: C/D layout col=lane&15, row=(lane>>4)*4+reg (verified)
    const int gcol0 = bn * 256 + wc * 64 + (lane & 15);
    float ac4[4];
#pragma unroll
    for (int j = 0; j < 4; ++j) ac4[j] = (float)acol[gcol0 + j * 16];

    const size_t grow0 = (size_t)bm * 256 + wr * 128 + (lane >> 4) * 4;
#pragma unroll
    for (int i = 0; i < 8; ++i) {
#pragma unroll
        for (int r = 0; r < 4; ++r) {
            const size_t row = grow0 + i * 16 + r;
            const float ar = (float)arow[row];
            _Float16* outp = Cout + row * (size_t)N_DIM + gcol0;
#pragma unroll
            for (int j = 0; j < 4; ++j) {
                float v = (float)acc[i][j][r] * ar * ac4[j];
                outp[j * 16] = (_Float16)v;
            }
        }
    }
}

// ---------------------------------------------------------------------------
extern "C" void kernel_launch(void* const* d_in, const int* in_sizes, int n_in,
                              void* d_out, int out_size, void* d_ws, size_t ws_size,
                              hipStream_t stream) {
    const int* a = (const int*)d_in[0];             // [M,K] int32 (int8 values)
    const int* b = (const int*)d_in[1];             // [N,K] int32 (int8 values)
    const _Float16* ar = (const _Float16*)d_in[2];  // [M] fp16
    const _Float16* ac = (const _Float16*)d_in[3];  // [N] fp16
    _Float16* out = (_Float16*)d_out;               // [M,N] fp16

    unsigned char* pa = (unsigned char*)d_ws;        // 16 MB
    unsigned char* pb = pa + (size_t)M_DIM * K_DIM;  // 32 MB

    const size_t total_frag = (size_t)(M_DIM / 16 + N_DIM / 16) * (K_DIM / 64) * 64;
    pack_frag<<<(int)(total_frag / 256), 256, 0, stream>>>(a, b, pa, pb);

    dim3 grid(N_DIM / 256, M_DIM / 256);
    gemm_i8<<<grid, 512, 0, stream>>>(pa, pb, ar, ac, out);
}

// Round 3
// 359.186 us; speedup vs baseline: 1.0607x; 1.0607x over previous
//
#include <hip/hip_runtime.h>
#include <cstdint>
#include <cstddef>

#define M_DIM 4096
#define N_DIM 8192
#define K_DIM 4096

typedef __attribute__((ext_vector_type(4))) int int4v;

// ---------------------------------------------------------------------------
// Pack into MFMA-fragment order (int32 -> int8). R3/R8-verified, identical.
// p = 16-row panel, s = 64-byte kstep, lane l: chunk(p,s) is 1024 B where
// lane l holds row 16p+(l&15), k-bytes s*64 + (l>>4)*16 .. +16.
// ---------------------------------------------------------------------------
__global__ void __launch_bounds__(256) pack_frag(const int* __restrict__ a,
                                                 const int* __restrict__ b,
                                                 unsigned char* __restrict__ pa,
                                                 unsigned char* __restrict__ pb) {
    size_t t = (size_t)blockIdx.x * 256 + threadIdx.x;
    const size_t NA = (size_t)(M_DIM / 16) * (K_DIM / 64) * 64;
    const int* __restrict__ src;
    unsigned char* __restrict__ dst;
    if (t < NA) {
        src = a; dst = pa;
    } else {
        src = b; dst = pb; t -= NA;
    }
    const int l = (int)(t & 63);
    const int s = (int)((t >> 6) & 63);
    const int p = (int)(t >> 12);
    const int* g = src + ((size_t)(16 * p + (l & 15))) * K_DIM + s * 64 + (l >> 4) * 16;
    const int4v* g4 = (const int4v*)g;
    int4v o;
#pragma unroll
    for (int q = 0; q < 4; ++q) {
        int4v v = g4[q];
        o[q] = (v[0] & 0xff) | ((v[1] & 0xff) << 8) | ((v[2] & 0xff) << 16) | (v[3] << 24);
    }
    ((int4v*)dst)[t] = o;
}

// ---------------------------------------------------------------------------
// GEMM: block 128(M) x 256(N), 256 thr = 4 waves, wave tile 64x128,
// mfma_i32_16x16x64_i8, BK=64 — R12's verified geometry/epilogue.
// CHANGES vs R12 (131.6 us, MfmaUtil 44%):
//   * TRIPLE-buffered LDS (3 x 24 KB = 72 KB; still 2 blocks/CU at 144 KB,
//     preserving R12's independent-barrier-domain overlap across blocks).
//   * Tile boundary = raw s_barrier + COUNTED s_waitcnt vmcnt(6): tile T+2's
//     6 DMA loads stay in flight across the barrier; tile T+1's loads were
//     issued a full tile earlier so the wait is ~free. This removes the
//     __syncthreads() vmcnt(0)+lgkmcnt(0) full drain that stalled R12
//     (the documented ~20% barrier-drain stall), and with NO intra-tile
//     barriers the 8 resident waves/CU drift so ds_read and MFMA pipes
//     co-schedule across waves (m114) instead of summing.
//   * s_setprio(1) around the MFMA cluster (T5: pays when waves drift).
// Correctness of buffer rotation: DMA for T+2 writes o_pre, whose last
// readers (tile T-1's ds_reads) completed before the T-1 boundary barrier
// (every read is consumed by an MFMA, whose compiler-inserted lgkmcnt wait
// forces completion); the barrier makes that block-wide before any T DMA.
// ---------------------------------------------------------------------------
__device__ inline void async_copy16(const unsigned char* g, unsigned char* l) {
    __builtin_amdgcn_global_load_lds(
        (const __attribute__((address_space(1))) void*)g,
        (__attribute__((address_space(3))) void*)l,
        16, 0, 0);
}

#define BAR() __builtin_amdgcn_s_barrier()

__global__ void __launch_bounds__(256, 2) gemm_i8(const unsigned char* __restrict__ Ap,
                                                  const unsigned char* __restrict__ Bp,
                                                  const _Float16* __restrict__ arow,
                                                  const _Float16* __restrict__ acol,
                                                  _Float16* __restrict__ Cout) {
    // buffer b at b*24576: A panels [0,8K), B panels [8K,24K)
    __shared__ __align__(16) unsigned char lds[3 * 24576];

    const int tid  = threadIdx.x;
    const int lane = tid & 63;
    const int wave = tid >> 6;        // 0..3
    const int bn   = blockIdx.x;      // 0..31 (256 cols)
    const int bm   = blockIdx.y;      // 0..31 (128 rows)

    const int pm0 = (wave & 1) * 4;   // A panel base (4 panels = 64 rows)
    const int pn0 = (wave >> 1) * 8;  // B panel base (8 panels = 128 cols)

    // staging: wave w stages A panels {2w,2w+1} (2 chunks) and
    // B panels {4w..4w+3} (4 chunks); 24 chunks = 24 KB per tile per block.
    const unsigned char* ag[2];
    int salo[2];
#pragma unroll
    for (int r = 0; r < 2; ++r) {
        const int p = 2 * wave + r;
        ag[r]   = Ap + (size_t)(bm * 8 + p) * 65536 + lane * 16;
        salo[r] = p * 1024;  // wave-uniform; HW adds lane*16
    }
    const unsigned char* bg[4];
    int sblo[4];
#pragma unroll
    for (int r = 0; r < 4; ++r) {
        const int p = 4 * wave + r;
        bg[r]   = Bp + (size_t)(bn * 16 + p) * 65536 + lane * 16;
        sblo[r] = 8192 + p * 1024;
    }

    const int a_off = pm0 * 1024 + lane * 16;         // + i*1024
    const int b_off = 8192 + pn0 * 1024 + lane * 16;  // + j*1024

    int4v acc[4][8];
#pragma unroll
    for (int i = 0; i < 4; ++i)
#pragma unroll
        for (int j = 0; j < 8; ++j) acc[i][j] = (int4v)0;

    const int NT = K_DIM / 64;  // 64

    // prologue: stage tile 0 -> buf0, tile 1 -> buf1 (12 loads in flight)
#pragma unroll
    for (int t = 0; t < 2; ++t) {
        const size_t gk = (size_t)t * 1024;
        const int lo = t * 24576;
#pragma unroll
        for (int r = 0; r < 2; ++r) async_copy16(ag[r] + gk, lds + lo + salo[r]);
#pragma unroll
        for (int r = 0; r < 4; ++r) async_copy16(bg[r] + gk, lds + lo + sblo[r]);
    }
    asm volatile("s_waitcnt vmcnt(6)" ::: "memory");  // tile0 landed, tile1 in flight
    BAR();

    int o_cur = 0, o_nxt = 24576, o_pre = 49152;

#pragma unroll 3
    for (int T = 0; T < NT; ++T) {
        const bool pre = (T + 2 < NT);  // uniform
        const unsigned char* Ac = lds + o_cur;

        // issue DMA for tile T+2 into o_pre (left in flight across boundary)
        if (pre) {
            const size_t gk2 = (size_t)(T + 2) * 1024;
#pragma unroll
            for (int r = 0; r < 2; ++r)
                async_copy16(ag[r] + gk2, lds + o_pre + salo[r]);
#pragma unroll
            for (int r = 0; r < 4; ++r)
                async_copy16(bg[r] + gk2, lds + o_pre + sblo[r]);
        }

        // bulk fragment reads, compiler-scheduled fine-grained lgkmcnt
        int4v af[4], bf[8];
#pragma unroll
        for (int i = 0; i < 4; ++i)
            af[i] = *(const int4v*)(Ac + a_off + i * 1024);
#pragma unroll
        for (int j = 0; j < 8; ++j)
            bf[j] = *(const int4v*)(Ac + b_off + j * 1024);

        __builtin_amdgcn_s_setprio(1);
#pragma unroll
        for (int i = 0; i < 4; ++i)
#pragma unroll
            for (int j = 0; j < 8; ++j)
                acc[i][j] = __builtin_amdgcn_mfma_i32_16x16x64_i8(af[i], bf[j],
                                                                  acc[i][j], 0, 0, 0);
        __builtin_amdgcn_s_setprio(0);

        // boundary: COUNTED wait — tile T+1 landed, T+2's 6 stay in flight
        if (pre) {
            asm volatile("s_waitcnt vmcnt(6)" ::: "memory");
        } else {
            asm volatile("s_waitcnt vmcnt(0)" ::: "memory");
        }
        BAR();

        const int t0 = o_cur; o_cur = o_nxt; o_nxt = o_pre; o_pre = t0;
    }

    // --- epilogue: C/D layout col=lane&15, row=(lane>>4)*4+reg (verified)
    const int gcol0 = bn * 256 + pn0 * 16 + (lane & 15);
    float ac8[8];
#pragma unroll
    for (int j = 0; j < 8; ++j) ac8[j] = (float)acol[gcol0 + j * 16];

    const size_t grow0 = (size_t)bm * 128 + pm0 * 16 + (lane >> 4) * 4;
#pragma unroll
    for (int i = 0; i < 4; ++i) {
#pragma unroll
        for (int r = 0; r < 4; ++r) {
            const size_t row = grow0 + i * 16 + r;
            const float ar = (float)arow[row];
            _Float16* outp = Cout + row * (size_t)N_DIM + gcol0;
#pragma unroll
            for (int j = 0; j < 8; ++j) {
                float v = (float)acc[i][j][r] * ar * ac8[j];
                outp[j * 16] = (_Float16)v;
            }
        }
    }
}

// ---------------------------------------------------------------------------
extern "C" void kernel_launch(void* const* d_in, const int* in_sizes, int n_in,
                              void* d_out, int out_size, void* d_ws, size_t ws_size,
                              hipStream_t stream) {
    const int* a = (const int*)d_in[0];             // [M,K] int32 (int8 values)
    const int* b = (const int*)d_in[1];             // [N,K] int32 (int8 values)
    const _Float16* ar = (const _Float16*)d_in[2];  // [M] fp16
    const _Float16* ac = (const _Float16*)d_in[3];  // [N] fp16
    _Float16* out = (_Float16*)d_out;               // [M,N] fp16

    unsigned char* pa = (unsigned char*)d_ws;        // 16 MB
    unsigned char* pb = pa + (size_t)M_DIM * K_DIM;  // 32 MB

    const size_t total_frag = (size_t)(M_DIM / 16 + N_DIM / 16) * (K_DIM / 64) * 64;
    pack_frag<<<(int)(total_frag / 256), 256, 0, stream>>>(a, b, pa, pb);

    dim3 grid(N_DIM / 256, M_DIM / 128);
    gemm_i8<<<grid, 256, 0, stream>>>(pa, pb, ar, ac, out);
}